// Round 4
// baseline (458.443 us; speedup 1.0000x reference)
//
#include <hip/hip_runtime.h>
#include <cstdint>
#include <cstddef>

#define N_PTS 50000
#define H 16
#define CIN 256
#define C 256
#define CPG 32
#define CR 64

typedef short bf16x8 __attribute__((ext_vector_type(8)));
typedef float f32x4 __attribute__((ext_vector_type(4)));

__device__ __forceinline__ unsigned short f2bf(float f) {
    unsigned int u = __float_as_uint(f);
    u += 0x7fff + ((u >> 16) & 1);
    return (unsigned short)(u >> 16);
}
__device__ __forceinline__ float bf2f(unsigned short s) {
    return __uint_as_float(((unsigned int)s) << 16);
}
__device__ __forceinline__ void async_load16(const void* g, void* l) {
    __builtin_amdgcn_global_load_lds(
        (const __attribute__((address_space(1))) unsigned int*)g,
        (__attribute__((address_space(3))) unsigned int*)l, 16, 0, 0);
}

// ---------------------------------------------------------------------------
// Merged prep: [0,6250) convert s_feats->bf16; [6250,6346) pack Wq|Wk|Wv
// B-frags; [6346,6359) pack Wd2/Wa1/Wa2 B-frags.
//   frag(kt,nt): lane l holds B[kt*32+(l>>4)*8+j][nt*16+(l&15)], j=0..7
// ---------------------------------------------------------------------------
__global__ __launch_bounds__(256) void prep_all(
    const float* __restrict__ feats,
    const float* __restrict__ Wq, const float* __restrict__ Wk,
    const float* __restrict__ Wv,
    const float* __restrict__ Wd2, const float* __restrict__ Wa1,
    const float* __restrict__ Wa2,
    unsigned short* __restrict__ A_bf16,
    unsigned short* __restrict__ gemmFrags,
    unsigned short* __restrict__ attnFrags)
{
    int bid = blockIdx.x;
    if (bid < 6250) {
        size_t i = ((size_t)bid * 256 + threadIdx.x) * 8;
        float4 f0 = *(const float4*)&feats[i];
        float4 f1 = *(const float4*)&feats[i + 4];
        unsigned short t[8] = {f2bf(f0.x), f2bf(f0.y), f2bf(f0.z), f2bf(f0.w),
                               f2bf(f1.x), f2bf(f1.y), f2bf(f1.z), f2bf(f1.w)};
        *(bf16x8*)&A_bf16[i] = *(bf16x8*)t;
    } else if (bid < 6346) {
        int t = (bid - 6250) * 256 + threadIdx.x;   // 0..24575
        int lane = t & 63;
        int f = t >> 6;                              // kt*48 + ntg
        int ntg = f % 48;
        const float* W = ntg < 16 ? Wq : (ntg < 32 ? Wk : Wv);
        int colc = (ntg & 15) * 16 + (lane & 15);
        int row0 = (f / 48) * 32 + ((lane >> 4) << 3);
        unsigned short tmp[8];
        #pragma unroll
        for (int j = 0; j < 8; ++j) tmp[j] = f2bf(W[(size_t)(row0 + j) * 256 + colc]);
        *(bf16x8*)&gemmFrags[(size_t)t * 8] = *(bf16x8*)tmp;
    } else {
        int t = (bid - 6346) * 256 + threadIdx.x;
        if (t >= 3200) return;
        const float* W; int Nc, NT, loc, base;
        if (t < 2048)      { W = Wd2; Nc = 256; NT = 16; loc = t;        base = 0; }
        else if (t < 3072) { W = Wa1; Nc = 32;  NT = 2;  loc = t - 2048; base = 16384; }
        else               { W = Wa2; Nc = 32;  NT = 2;  loc = t - 3072; base = 24576; }
        int f = loc >> 6, lane = loc & 63;
        int kt = f / NT, nt = f - kt * NT;
        int colc = nt * 16 + (lane & 15);
        int row0 = kt * 32 + ((lane >> 4) << 3);
        unsigned short tmp[8];
        #pragma unroll
        for (int j = 0; j < 8; ++j) tmp[j] = f2bf(W[(size_t)(row0 + j) * Nc + colc]);
        *(bf16x8*)&attnFrags[(size_t)(base + loc * 8)] = *(bf16x8*)tmp;
    }
}

// ---------------------------------------------------------------------------
// QKV GEMM v2: full 128x256 A-tile resident in LDS (async-staged, XOR-swizzled),
// ONE barrier, K-loop = pure B-frag stream + MFMA (no barriers, compiler vmcnt).
// Output bf16 [N][768]: [0..255]=q, [256+2c]=k[c], [257+2c]=v[c].
// ---------------------------------------------------------------------------
__global__ __launch_bounds__(256) void qkv_gemm_mfma(
    const unsigned short* __restrict__ A,       // [N][256] bf16
    const unsigned short* __restrict__ wfrags,
    const float* __restrict__ bq, const float* __restrict__ bk,
    const float* __restrict__ bv, unsigned short* __restrict__ out)
{
    __shared__ unsigned short s_a[128 * 256];   // 64 KB, chunk-XOR swizzled
    const int tid = threadIdx.x;
    const int lane = tid & 63, wave = tid >> 6;
    const int quad = lane >> 4, col16 = lane & 15;
    const int bx = blockIdx.x, by = blockIdx.y;
    const int row0 = by * 128;

    // stage A: 16 issues/wave, each 64 lanes x 16B = 1KB contiguous LDS.
    // LDS ushort offset o = base + lane*8; row = o>>8; chunk cb=(o>>3)&31
    // holds global chunk cb ^ ((row&7)<<2)  (swizzle applied on global side).
    #pragma unroll
    for (int t = 0; t < 16; ++t) {
        int base = (wave * 16 + t) * 512;       // ushort units
        int o = base + lane * 8;
        int row = o >> 8;
        int cb = (o >> 3) & 31;
        int cbo = cb ^ ((row & 7) << 2);
        int gr = row0 + row;
        if (gr >= N_PTS) gr = N_PTS - 1;        // safe clamp; rows masked at store
        async_load16(A + (size_t)gr * 256 + cbo * 8, s_a + base);
    }
    __syncthreads();

    // A fragments: loop-invariant, hoisted. row&7 == col16&7 within a quad read,
    // so the XOR spreads the 16 rows across all 32 banks (2-way = free).
    bf16x8 af[2][8];
    #pragma unroll
    for (int mt = 0; mt < 2; ++mt) {
        int row = wave * 32 + mt * 16 + col16;
        int rsw = (row & 7) << 5;               // ushort-domain xor
        #pragma unroll
        for (int kt = 0; kt < 8; ++kt) {
            int uo = (kt * 32 + quad * 8) ^ rsw;
            af[mt][kt] = *(const bf16x8*)&s_a[row * 256 + uo];
        }
    }

    f32x4 acc[2][8] = {};
    #pragma unroll
    for (int kt = 0; kt < 8; ++kt) {
        #pragma unroll
        for (int nt = 0; nt < 8; ++nt) {
            bf16x8 bf = *(const bf16x8*)&wfrags[(((size_t)kt * 48 + bx * 8 + nt) * 64 + lane) * 8];
            acc[0][nt] = __builtin_amdgcn_mfma_f32_16x16x32_bf16(af[0][kt], bf, acc[0][nt], 0, 0, 0);
            acc[1][nt] = __builtin_amdgcn_mfma_f32_16x16x32_bf16(af[1][kt], bf, acc[1][nt], 0, 0, 0);
        }
    }

    const int mode = bx >> 1;   // 0=q 1=k 2=v
    const float* bias = mode == 0 ? bq : (mode == 1 ? bk : bv);
    #pragma unroll
    for (int nt = 0; nt < 8; ++nt) {
        int cIn = (bx & 1) * 128 + nt * 16 + col16;
        float bb = bias[cIn];
        int pos = mode == 0 ? cIn : (256 + 2 * cIn + (mode == 2 ? 1 : 0));
        #pragma unroll
        for (int mt = 0; mt < 2; ++mt) {
            #pragma unroll
            for (int r = 0; r < 4; ++r) {
                int row = row0 + wave * 32 + mt * 16 + quad * 4 + r;
                if (row < N_PTS)
                    out[(size_t)row * 768 + pos] = f2bf(acc[mt][nt][r] + bb);
            }
        }
    }
}

// ---------------------------------------------------------------------------
// Fused attention: 4 points per block (sequential), weight frags in registers.
// s_geom now bf16 (stride 268 -> bank-clean quad-scatter writes).
// ---------------------------------------------------------------------------
#define D1S 72
#define GSB 268
#define QKS 264
#define A1S 40
#define A2S 33

__global__ __launch_bounds__(256) void attn_mfma(
    const unsigned short* __restrict__ qkv,     // [N][768] q | kv-interleaved
    const float* __restrict__ q_pts, const float* __restrict__ s_pts,
    const int* __restrict__ nbr,
    const float* __restrict__ Wd1, const float* __restrict__ bd1,
    const float* __restrict__ bd2,
    const unsigned short* __restrict__ frags,
    const float* __restrict__ ba1, const float* __restrict__ ba2,
    float* __restrict__ out)
{
    __shared__ unsigned short s_d1[H * D1S];
    __shared__ unsigned short s_geom[H * GSB];
    __shared__ unsigned short s_qk[H * QKS];
    __shared__ unsigned short s_a1[H * A1S];
    __shared__ float          s_a2[H * A2S];
    __shared__ float          s_rel[4][H][3];
    __shared__ int            s_idx[4][H];

    const int tid = threadIdx.x;
    const int lane = tid & 63, wave = tid >> 6;
    const int quad = lane >> 4, col = lane & 15;
    const int n0 = blockIdx.x * 4;
    const int c = tid;

    if (tid < 64) {
        int pp = tid >> 4, hh = tid & 15;
        int idx = nbr[(size_t)(n0 + pp) * H + hh];
        s_idx[pp][hh] = idx;
        #pragma unroll
        for (int x = 0; x < 3; ++x)
            s_rel[pp][hh][x] = s_pts[(size_t)idx * 3 + x] - q_pts[(size_t)(n0 + pp) * 3 + x];
    }

    const float w1x = Wd1[lane], w1y = Wd1[64 + lane], w1z = Wd1[128 + lane];
    const float b1 = bd1[lane];
    const float b2 = bd2[c];
    bf16x8 wd2f[2][4];
    #pragma unroll
    for (int t = 0; t < 4; ++t) {
        wd2f[0][t] = *(const bf16x8*)&frags[((size_t)((0 * 16 + wave * 4 + t) * 64 + lane)) * 8];
        wd2f[1][t] = *(const bf16x8*)&frags[((size_t)((1 * 16 + wave * 4 + t) * 64 + lane)) * 8];
    }
    bf16x8 wa1f[8];
    bf16x8 wa2f = {0,0,0,0,0,0,0,0};
    if (wave < 2) {
        #pragma unroll
        for (int kt = 0; kt < 8; ++kt)
            wa1f[kt] = *(const bf16x8*)&frags[16384 + ((size_t)((kt * 2 + wave) * 64 + lane)) * 8];
        wa2f = *(const bf16x8*)&frags[24576 + ((size_t)(wave * 64 + lane)) * 8];
    }
    __syncthreads();

    for (int p = 0; p < 4; ++p) {
        const int n = n0 + p;

        #pragma unroll
        for (int pass = 0; pass < 4; ++pass) {
            int h = pass * 4 + wave;
            float v = b1 + s_rel[p][h][0] * w1x + s_rel[p][h][1] * w1y + s_rel[p][h][2] * w1z;
            s_d1[h * D1S + lane] = f2bf(fmaxf(v, 0.1f * v));
        }
        __syncthreads();

        // geom = d1 @ Wd2 (16x64 @ 64x256) -> bf16 LDS
        {
            bf16x8 ga = *(bf16x8*)&s_d1[col * D1S + quad * 8];
            bf16x8 gb = *(bf16x8*)&s_d1[col * D1S + 32 + quad * 8];
            #pragma unroll
            for (int t = 0; t < 4; ++t) {
                f32x4 acc = {0.f, 0.f, 0.f, 0.f};
                acc = __builtin_amdgcn_mfma_f32_16x16x32_bf16(ga, wd2f[0][t], acc, 0, 0, 0);
                acc = __builtin_amdgcn_mfma_f32_16x16x32_bf16(gb, wd2f[1][t], acc, 0, 0, 0);
                int nt = wave * 4 + t;
                #pragma unroll
                for (int rr = 0; rr < 4; ++rr)
                    s_geom[(quad * 4 + rr) * GSB + nt * 16 + col] = f2bf(acc[rr]);
            }
        }
        __syncthreads();

        // elementwise: gather kv dword, build vg (regs) + qk (LDS)
        float qf = bf2f(qkv[(size_t)s_idx[p][0] * 768 + c]);
        float vg[H];
        #pragma unroll
        for (int h = 0; h < H; ++h) {
            int idx = s_idx[p][h];
            unsigned int u = *(const unsigned int*)&qkv[(size_t)idx * 768 + 256 + 2 * c];
            float nk = __uint_as_float(u << 16);
            float nv = __uint_as_float(u & 0xffff0000u);
            float g = bf2f(s_geom[h * GSB + c]) + b2;
            vg[h] = nv - g;
            float tq = qf - nk - g;
            s_qk[h * QKS + c] = f2bf(fmaxf(tq, 0.1f * tq));
        }
        __syncthreads();

        if (wave < 2) {
            f32x4 acc = {0.f, 0.f, 0.f, 0.f};
            #pragma unroll
            for (int kt = 0; kt < 8; ++kt) {
                bf16x8 a = *(bf16x8*)&s_qk[col * QKS + kt * 32 + quad * 8];
                acc = __builtin_amdgcn_mfma_f32_16x16x32_bf16(a, wa1f[kt], acc, 0, 0, 0);
            }
            int j = wave * 16 + col;
            float bb = ba1[j];
            #pragma unroll
            for (int rr = 0; rr < 4; ++rr) {
                float v = acc[rr] + bb;
                s_a1[(quad * 4 + rr) * A1S + j] = f2bf(fmaxf(v, 0.1f * v));
            }
        }
        __syncthreads();

        if (wave < 2) {
            bf16x8 aa = *(bf16x8*)&s_a1[col * A1S + quad * 8];
            f32x4 acc = {0.f, 0.f, 0.f, 0.f};
            acc = __builtin_amdgcn_mfma_f32_16x16x32_bf16(aa, wa2f, acc, 0, 0, 0);
            int j = wave * 16 + col;
            float bb = ba2[j];
            #pragma unroll
            for (int rr = 0; rr < 4; ++rr)
                s_a2[(quad * 4 + rr) * A2S + j] = acc[rr] + bb;
        }
        __syncthreads();

        if (wave == 0) {
            int j = lane & 31, hb = (lane >> 5) * 8;
            float vals[8];
            float mx = -1e30f;
            #pragma unroll
            for (int i = 0; i < 8; ++i) {
                vals[i] = s_a2[(hb + i) * A2S + j];
                mx = fmaxf(mx, vals[i]);
            }
            mx = fmaxf(mx, __shfl_xor(mx, 32));
            float sum = 0.f;
            #pragma unroll
            for (int i = 0; i < 8; ++i) { vals[i] = __expf(vals[i] - mx); sum += vals[i]; }
            sum += __shfl_xor(sum, 32);
            float inv = 1.f / sum;
            #pragma unroll
            for (int i = 0; i < 8; ++i) s_a2[(hb + i) * A2S + j] = vals[i] * inv;
        }
        __syncthreads();

        float o = 0.f;
        const int aj = c >> 3;
        #pragma unroll
        for (int h = 0; h < H; ++h) o += vg[h] * s_a2[h * A2S + aj];
        out[(size_t)n * C + c] = o;
    }
}

// ---------------------------------------------------------------------------

extern "C" void kernel_launch(void* const* d_in, const int* in_sizes, int n_in,
                              void* d_out, int out_size, void* d_ws, size_t ws_size,
                              hipStream_t stream) {
    const float* q_pts   = (const float*)d_in[0];
    const float* s_pts   = (const float*)d_in[1];
    const float* s_feats = (const float*)d_in[2];
    const int*   nbr     = (const int*)d_in[3];
    const float* Wq  = (const float*)d_in[4];
    const float* bq  = (const float*)d_in[5];
    const float* Wk  = (const float*)d_in[6];
    const float* bk  = (const float*)d_in[7];
    const float* Wv  = (const float*)d_in[8];
    const float* bv  = (const float*)d_in[9];
    const float* Wd1 = (const float*)d_in[10];
    const float* bd1 = (const float*)d_in[11];
    const float* Wd2 = (const float*)d_in[12];
    const float* bd2 = (const float*)d_in[13];
    const float* Wa1 = (const float*)d_in[14];
    const float* ba1 = (const float*)d_in[15];
    const float* Wa2 = (const float*)d_in[16];
    const float* ba2 = (const float*)d_in[17];

    float* out = (float*)d_out;
    char* ws = (char*)d_ws;
    unsigned short* A_bf16    = (unsigned short*)(ws);                 // 25.6 MB
    unsigned short* qkvb      = (unsigned short*)(ws + 25600000);      // 76.8 MB
    unsigned short* attnFrags = (unsigned short*)(ws + 102400000);     // 51.2 KB
    unsigned short* gemmFrags = (unsigned short*)(ws + 102451200);     // 384 KB

    prep_all<<<6359, 256, 0, stream>>>(s_feats, Wq, Wk, Wv, Wd2, Wa1, Wa2,
                                       A_bf16, gemmFrags, attnFrags);

    dim3 g1(6, (N_PTS + 127) / 128);
    qkv_gemm_mfma<<<g1, 256, 0, stream>>>(A_bf16, gemmFrags, bq, bk, bv, qkvb);

    attn_mfma<<<(N_PTS / 4), 256, 0, stream>>>(qkvb, q_pts, s_pts, nbr,
                                               Wd1, bd1, bd2, attnFrags,
                                               ba1, ba2, out);
}

// Round 5
// 404.127 us; speedup vs baseline: 1.1344x; 1.1344x over previous
//
#include <hip/hip_runtime.h>
#include <cstdint>
#include <cstddef>

#define N_PTS 50000
#define H 16
#define CIN 256
#define C 256
#define CPG 32
#define CR 64

typedef short bf16x8 __attribute__((ext_vector_type(8)));
typedef float f32x4 __attribute__((ext_vector_type(4)));

__device__ __forceinline__ unsigned short f2bf(float f) {
    unsigned int u = __float_as_uint(f);
    u += 0x7fff + ((u >> 16) & 1);
    return (unsigned short)(u >> 16);
}
__device__ __forceinline__ float bf2f(unsigned short s) {
    return __uint_as_float(((unsigned int)s) << 16);
}

// ---------------------------------------------------------------------------
// Merged prep: [0,6250) convert s_feats->bf16; [6250,6346) pack Wq|Wk|Wv
// B-frags; [6346,6359) pack Wd2/Wa1/Wa2 B-frags.
//   frag(kt,nt): lane l holds B[kt*32+(l>>4)*8+j][nt*16+(l&15)], j=0..7
// ---------------------------------------------------------------------------
__global__ __launch_bounds__(256) void prep_all(
    const float* __restrict__ feats,
    const float* __restrict__ Wq, const float* __restrict__ Wk,
    const float* __restrict__ Wv,
    const float* __restrict__ Wd2, const float* __restrict__ Wa1,
    const float* __restrict__ Wa2,
    unsigned short* __restrict__ A_bf16,
    unsigned short* __restrict__ gemmFrags,
    unsigned short* __restrict__ attnFrags)
{
    int bid = blockIdx.x;
    if (bid < 6250) {
        size_t i = ((size_t)bid * 256 + threadIdx.x) * 8;
        float4 f0 = *(const float4*)&feats[i];
        float4 f1 = *(const float4*)&feats[i + 4];
        unsigned short t[8] = {f2bf(f0.x), f2bf(f0.y), f2bf(f0.z), f2bf(f0.w),
                               f2bf(f1.x), f2bf(f1.y), f2bf(f1.z), f2bf(f1.w)};
        *(bf16x8*)&A_bf16[i] = *(bf16x8*)t;
    } else if (bid < 6346) {
        int t = (bid - 6250) * 256 + threadIdx.x;   // 0..24575
        int lane = t & 63;
        int f = t >> 6;                              // kt*48 + ntg
        int ntg = f % 48;
        const float* W = ntg < 16 ? Wq : (ntg < 32 ? Wk : Wv);
        int colc = (ntg & 15) * 16 + (lane & 15);
        int row0 = (f / 48) * 32 + ((lane >> 4) << 3);
        unsigned short tmp[8];
        #pragma unroll
        for (int j = 0; j < 8; ++j) tmp[j] = f2bf(W[(size_t)(row0 + j) * 256 + colc]);
        *(bf16x8*)&gemmFrags[(size_t)t * 8] = *(bf16x8*)tmp;
    } else {
        int t = (bid - 6346) * 256 + threadIdx.x;
        if (t >= 3200) return;
        const float* W; int Nc, NT, loc, base;
        if (t < 2048)      { W = Wd2; Nc = 256; NT = 16; loc = t;        base = 0; }
        else if (t < 3072) { W = Wa1; Nc = 32;  NT = 2;  loc = t - 2048; base = 16384; }
        else               { W = Wa2; Nc = 32;  NT = 2;  loc = t - 3072; base = 24576; }
        int f = loc >> 6, lane = loc & 63;
        int kt = f / NT, nt = f - kt * NT;
        int colc = nt * 16 + (lane & 15);
        int row0 = kt * 32 + ((lane >> 4) << 3);
        unsigned short tmp[8];
        #pragma unroll
        for (int j = 0; j < 8; ++j) tmp[j] = f2bf(W[(size_t)(row0 + j) * Nc + colc]);
        *(bf16x8*)&attnFrags[(size_t)(base + loc * 8)] = *(bf16x8*)tmp;
    }
}

// ---------------------------------------------------------------------------
// QKV GEMM (v1, round-3 verified): [50000x256] @ [256x768] -> bf16 [N][768],
// kv interleaved: row = [0..255]=q, [256+2c]=k[c], [257+2c]=v[c].
// 128x128 tile, 4 waves, per-kt LDS staging.
// ---------------------------------------------------------------------------
__global__ __launch_bounds__(256) void qkv_gemm_mfma(
    const unsigned short* __restrict__ A,       // [N][256] bf16
    const unsigned short* __restrict__ wfrags,
    const float* __restrict__ bq, const float* __restrict__ bk,
    const float* __restrict__ bv, unsigned short* __restrict__ out)
{
    __shared__ unsigned short s_a[128 * 40];    // stride 40 -> 2-way-free banks
    const int tid = threadIdx.x;
    const int lane = tid & 63, wave = tid >> 6;
    const int quad = lane >> 4, col16 = lane & 15;
    const int bx = blockIdx.x, by = blockIdx.y;

    f32x4 acc[2][8] = {};
    const int mrow = tid >> 1, half = tid & 1;
    const int gm = by * 128 + mrow;

    for (int kt = 0; kt < 8; ++kt) {
        bf16x8 a0 = {0,0,0,0,0,0,0,0}, a1 = a0;
        if (gm < N_PTS) {
            const unsigned short* src = &A[(size_t)gm * 256 + kt * 32 + half * 16];
            a0 = *(const bf16x8*)src;
            a1 = *(const bf16x8*)(src + 8);
        }
        __syncthreads();
        *(bf16x8*)&s_a[mrow * 40 + half * 16]     = a0;
        *(bf16x8*)&s_a[mrow * 40 + half * 16 + 8] = a1;
        __syncthreads();
        bf16x8 af0 = *(bf16x8*)&s_a[(wave * 32 + col16) * 40 + quad * 8];
        bf16x8 af1 = *(bf16x8*)&s_a[(wave * 32 + 16 + col16) * 40 + quad * 8];
        #pragma unroll
        for (int nt = 0; nt < 8; ++nt) {
            bf16x8 bf = *(const bf16x8*)&wfrags[(((size_t)kt * 48 + bx * 8 + nt) * 64 + lane) * 8];
            acc[0][nt] = __builtin_amdgcn_mfma_f32_16x16x32_bf16(af0, bf, acc[0][nt], 0, 0, 0);
            acc[1][nt] = __builtin_amdgcn_mfma_f32_16x16x32_bf16(af1, bf, acc[1][nt], 0, 0, 0);
        }
    }

    const int mode = bx >> 1;   // 0=q 1=k 2=v
    const float* bias = mode == 0 ? bq : (mode == 1 ? bk : bv);
    #pragma unroll
    for (int nt = 0; nt < 8; ++nt) {
        int cIn = (bx & 1) * 128 + nt * 16 + col16;
        float bb = bias[cIn];
        int pos = mode == 0 ? cIn : (256 + 2 * cIn + (mode == 2 ? 1 : 0));
        #pragma unroll
        for (int mt = 0; mt < 2; ++mt) {
            #pragma unroll
            for (int r = 0; r < 4; ++r) {
                int row = by * 128 + wave * 32 + mt * 16 + quad * 4 + r;
                if (row < N_PTS)
                    out[(size_t)row * 768 + pos] = f2bf(acc[mt][nt][r] + bb);
            }
        }
    }
}

// ---------------------------------------------------------------------------
// Fused attention v3: 4 points/block sequential, weight frags in registers.
// Changes vs round-3: (1) kv gathers issued after the d1 barrier, BEFORE the
// geom MFMAs; (2) geom C-tile goes to a WAVE-PRIVATE LDS region (no barrier
// between geom and its consumption -> gathers stay in flight).
// Channel mapping c = wave*64+lane == tid, identical to round-3 downstream.
// ---------------------------------------------------------------------------
#define D1S 72
#define PGS 66      // private geom row stride (dwords): 2-way banks on rd & wr
#define QKS 264
#define A1S 40
#define A2S 33

__global__ __launch_bounds__(256, 3) void attn_mfma(
    const unsigned short* __restrict__ qkv,     // [N][768] q | kv-interleaved
    const float* __restrict__ q_pts, const float* __restrict__ s_pts,
    const int* __restrict__ nbr,
    const float* __restrict__ Wd1, const float* __restrict__ bd1,
    const float* __restrict__ bd2,
    const unsigned short* __restrict__ frags,
    const float* __restrict__ ba1, const float* __restrict__ ba2,
    float* __restrict__ out)
{
    __shared__ unsigned short s_d1[H * D1S];
    __shared__ float          s_pg[4 * H * PGS];   // wave-private geom tiles
    __shared__ unsigned short s_qk[H * QKS];
    __shared__ unsigned short s_a1[H * A1S];
    __shared__ float          s_a2[H * A2S];
    __shared__ float          s_rel[4][H][3];
    __shared__ int            s_idx[4][H];

    const int tid = threadIdx.x;
    const int lane = tid & 63, wave = tid >> 6;
    const int quad = lane >> 4, col = lane & 15;
    const int n0 = blockIdx.x * 4;
    const int c = tid;                 // == wave*64 + lane

    if (tid < 64) {
        int pp = tid >> 4, hh = tid & 15;
        int idx = nbr[(size_t)(n0 + pp) * H + hh];
        s_idx[pp][hh] = idx;
        #pragma unroll
        for (int x = 0; x < 3; ++x)
            s_rel[pp][hh][x] = s_pts[(size_t)idx * 3 + x] - q_pts[(size_t)(n0 + pp) * 3 + x];
    }

    const float w1x = Wd1[lane], w1y = Wd1[64 + lane], w1z = Wd1[128 + lane];
    const float b1 = bd1[lane];
    const float b2 = bd2[c];
    bf16x8 wd2f[2][4];
    #pragma unroll
    for (int t = 0; t < 4; ++t) {
        wd2f[0][t] = *(const bf16x8*)&frags[((size_t)((0 * 16 + wave * 4 + t) * 64 + lane)) * 8];
        wd2f[1][t] = *(const bf16x8*)&frags[((size_t)((1 * 16 + wave * 4 + t) * 64 + lane)) * 8];
    }
    bf16x8 wa1f[8];
    bf16x8 wa2f = {0,0,0,0,0,0,0,0};
    if (wave < 2) {
        #pragma unroll
        for (int kt = 0; kt < 8; ++kt)
            wa1f[kt] = *(const bf16x8*)&frags[16384 + ((size_t)((kt * 2 + wave) * 64 + lane)) * 8];
        wa2f = *(const bf16x8*)&frags[24576 + ((size_t)(wave * 64 + lane)) * 8];
    }
    __syncthreads();

    float* pg = &s_pg[wave * (H * PGS)];

    for (int p = 0; p < 4; ++p) {
        const int n = n0 + p;

        // d1 = lrelu(rel @ Wd1 + bd1)  (cross-wave, needs the barrier below)
        #pragma unroll
        for (int pass = 0; pass < 4; ++pass) {
            int h = pass * 4 + wave;
            float v = b1 + s_rel[p][h][0] * w1x + s_rel[p][h][1] * w1y + s_rel[p][h][2] * w1z;
            s_d1[h * D1S + lane] = f2bf(fmaxf(v, 0.1f * v));
        }
        __syncthreads();

        // ---- issue all gathers now; no barrier until after they're consumed
        unsigned int u[H];
        #pragma unroll
        for (int h = 0; h < H; ++h)
            u[h] = *(const unsigned int*)&qkv[(size_t)s_idx[p][h] * 768 + 256 + 2 * c];
        float qf = bf2f(qkv[(size_t)s_idx[p][0] * 768 + c]);

        // geom = d1 @ Wd2 (16x64 @ 64x256) -> wave-private C-tile in LDS
        {
            bf16x8 ga = *(bf16x8*)&s_d1[col * D1S + quad * 8];
            bf16x8 gb = *(bf16x8*)&s_d1[col * D1S + 32 + quad * 8];
            #pragma unroll
            for (int t = 0; t < 4; ++t) {
                f32x4 acc = {0.f, 0.f, 0.f, 0.f};
                acc = __builtin_amdgcn_mfma_f32_16x16x32_bf16(ga, wd2f[0][t], acc, 0, 0, 0);
                acc = __builtin_amdgcn_mfma_f32_16x16x32_bf16(gb, wd2f[1][t], acc, 0, 0, 0);
                #pragma unroll
                for (int rr = 0; rr < 4; ++rr)
                    pg[(quad * 4 + rr) * PGS + t * 16 + col] = acc[rr];
            }
        }
        // same-wave ds_write -> ds_read: lgkmcnt only, NO __syncthreads here.

        // elementwise: consume gathered kv + private geom; build vg + qk
        float vg[H];
        #pragma unroll
        for (int h = 0; h < H; ++h) {
            float g = pg[h * PGS + lane] + b2;
            float nk = __uint_as_float(u[h] << 16);
            float nv = __uint_as_float(u[h] & 0xffff0000u);
            vg[h] = nv - g;
            float tq = qf - nk - g;
            s_qk[h * QKS + c] = f2bf(fmaxf(tq, 0.1f * tq));
        }
        __syncthreads();

        // a1 = lrelu(qk @ Wa1 + ba1) on waves 0,1
        if (wave < 2) {
            f32x4 acc = {0.f, 0.f, 0.f, 0.f};
            #pragma unroll
            for (int kt = 0; kt < 8; ++kt) {
                bf16x8 a = *(bf16x8*)&s_qk[col * QKS + kt * 32 + quad * 8];
                acc = __builtin_amdgcn_mfma_f32_16x16x32_bf16(a, wa1f[kt], acc, 0, 0, 0);
            }
            int j = wave * 16 + col;
            float bb = ba1[j];
            #pragma unroll
            for (int rr = 0; rr < 4; ++rr) {
                float v = acc[rr] + bb;
                s_a1[(quad * 4 + rr) * A1S + j] = f2bf(fmaxf(v, 0.1f * v));
            }
        }
        __syncthreads();

        // a2 = a1 @ Wa2 + ba2 on waves 0,1
        if (wave < 2) {
            bf16x8 aa = *(bf16x8*)&s_a1[col * A1S + quad * 8];
            f32x4 acc = {0.f, 0.f, 0.f, 0.f};
            acc = __builtin_amdgcn_mfma_f32_16x16x32_bf16(aa, wa2f, acc, 0, 0, 0);
            int j = wave * 16 + col;
            float bb = ba2[j];
            #pragma unroll
            for (int rr = 0; rr < 4; ++rr)
                s_a2[(quad * 4 + rr) * A2S + j] = acc[rr] + bb;
        }
        __syncthreads();

        // softmax over h, wave 0
        if (wave == 0) {
            int j = lane & 31, hb = (lane >> 5) * 8;
            float vals[8];
            float mx = -1e30f;
            #pragma unroll
            for (int i = 0; i < 8; ++i) {
                vals[i] = s_a2[(hb + i) * A2S + j];
                mx = fmaxf(mx, vals[i]);
            }
            mx = fmaxf(mx, __shfl_xor(mx, 32));
            float sum = 0.f;
            #pragma unroll
            for (int i = 0; i < 8; ++i) { vals[i] = __expf(vals[i] - mx); sum += vals[i]; }
            sum += __shfl_xor(sum, 32);
            float inv = 1.f / sum;
            #pragma unroll
            for (int i = 0; i < 8; ++i) s_a2[(hb + i) * A2S + j] = vals[i] * inv;
        }
        __syncthreads();

        // out[n][c] = sum_h vg[h] * attn[h][c>>3]
        float o = 0.f;
        const int aj = c >> 3;
        #pragma unroll
        for (int h = 0; h < H; ++h) o += vg[h] * s_a2[h * A2S + aj];
        out[(size_t)n * C + c] = o;
    }
}

// ---------------------------------------------------------------------------

extern "C" void kernel_launch(void* const* d_in, const int* in_sizes, int n_in,
                              void* d_out, int out_size, void* d_ws, size_t ws_size,
                              hipStream_t stream) {
    const float* q_pts   = (const float*)d_in[0];
    const float* s_pts   = (const float*)d_in[1];
    const float* s_feats = (const float*)d_in[2];
    const int*   nbr     = (const int*)d_in[3];
    const float* Wq  = (const float*)d_in[4];
    const float* bq  = (const float*)d_in[5];
    const float* Wk  = (const float*)d_in[6];
    const float* bk  = (const float*)d_in[7];
    const float* Wv  = (const float*)d_in[8];
    const float* bv  = (const float*)d_in[9];
    const float* Wd1 = (const float*)d_in[10];
    const float* bd1 = (const float*)d_in[11];
    const float* Wd2 = (const float*)d_in[12];
    const float* bd2 = (const float*)d_in[13];
    const float* Wa1 = (const float*)d_in[14];
    const float* ba1 = (const float*)d_in[15];
    const float* Wa2 = (const float*)d_in[16];
    const float* ba2 = (const float*)d_in[17];

    float* out = (float*)d_out;
    char* ws = (char*)d_ws;
    unsigned short* A_bf16    = (unsigned short*)(ws);                 // 25.6 MB
    unsigned short* qkvb      = (unsigned short*)(ws + 25600000);      // 76.8 MB
    unsigned short* attnFrags = (unsigned short*)(ws + 102400000);     // 51.2 KB
    unsigned short* gemmFrags = (unsigned short*)(ws + 102451200);     // 384 KB

    prep_all<<<6359, 256, 0, stream>>>(s_feats, Wq, Wk, Wv, Wd2, Wa1, Wa2,
                                       A_bf16, gemmFrags, attnFrags);

    dim3 g1(6, (N_PTS + 127) / 128);
    qkv_gemm_mfma<<<g1, 256, 0, stream>>>(A_bf16, gemmFrags, bq, bk, bv, qkvb);

    attn_mfma<<<(N_PTS / 4), 256, 0, stream>>>(qkvb, q_pts, s_pts, nbr,
                                               Wd1, bd1, bd2, attnFrags,
                                               ba1, ba2, out);
}